// Round 4
// baseline (4996.788 us; speedup 1.0000x reference)
//
#include <hip/hip_runtime.h>
#include <hip/hip_bf16.h>

typedef __hip_bfloat16 bf16;

#define NT   37824   // total tokens = 192*197
#define EDIM 768
#define N3   2304
#define TP   197     // tokens per frame
#define NB   16
#define NF   12
#define NH   12
#define HD   64
#define SCALE 0.125f
#define KALL 2364    // 12*197

__device__ __forceinline__ float bits2f(unsigned short u) {
    unsigned int v = ((unsigned int)u) << 16;
    return __uint_as_float(v);
}
__device__ __forceinline__ float b2f(bf16 v) { return __bfloat162float(v); }

__device__ __forceinline__ float4 load4(const float* p) { return *reinterpret_cast<const float4*>(p); }
__device__ __forceinline__ float4 load4(const bf16* p) {
    ushort4 u = *reinterpret_cast<const ushort4*>(p);
    return make_float4(bits2f(u.x), bits2f(u.y), bits2f(u.z), bits2f(u.w));
}
__device__ __forceinline__ void storeC(float* p, float v) { *p = v; }
__device__ __forceinline__ void storeC(bf16* p, float v) { *p = __float2bfloat16(v); }

// ---------------- K1: mid = x @ lora_a^T  (NT x 8), fp32 in ----------------
__global__ __launch_bounds__(256) void lora_mid_kernel(const float* __restrict__ x,
        const float* __restrict__ la, float* __restrict__ mid) {
    int t = blockIdx.x * 4 + (threadIdx.x >> 6);
    int lane = threadIdx.x & 63;
    if (t >= NT) return;
    float acc[8];
#pragma unroll
    for (int r = 0; r < 8; r++) acc[r] = 0.f;
    const float* xr = x + (size_t)t * EDIM;
    for (int e = lane; e < EDIM; e += 64) {
        float xv = xr[e];
#pragma unroll
        for (int r = 0; r < 8; r++) acc[r] += xv * la[r * EDIM + e];
    }
#pragma unroll
    for (int r = 0; r < 8; r++) {
        float v = acc[r];
#pragma unroll
        for (int off = 32; off >= 1; off >>= 1) v += __shfl_xor(v, off, 64);
        if (lane == 0) mid[(size_t)t * 8 + r] = v;
    }
}

// ---------------- Tiled SGEMM: C = A @ W^T + bias (+ mid @ lora_b^T) ----------------
// A: MxK (AT = float or bf16), W: NxK fp32, C: MxN (OT). 128x128 tile, TK=16, 8x8/thread.
template <typename AT, typename OT, bool LORA>
__global__ __launch_bounds__(256) void gemm_kernel(const AT* __restrict__ A,
        const float* __restrict__ W, const float* __restrict__ bias,
        const float* __restrict__ mid, const float* __restrict__ lb,
        OT* __restrict__ C, int M, int N, int K) {
    __shared__ float As[16][128];
    __shared__ float Bs[16][128];
    const int tid = threadIdx.x;
    const int tx = tid & 15, ty = tid >> 4;
    const int m0 = blockIdx.y * 128, n0 = blockIdx.x * 128;
    float acc[8][8];
#pragma unroll
    for (int i = 0; i < 8; i++) {
#pragma unroll
        for (int j = 0; j < 8; j++) acc[i][j] = 0.f;
    }
    const int rr = tid >> 2;
    const int c4 = (tid & 3) * 4;
    for (int k0 = 0; k0 < K; k0 += 16) {
#pragma unroll
        for (int ph = 0; ph < 2; ph++) {
            int r = rr + ph * 64;
            int m = m0 + r;
            float4 av = make_float4(0.f, 0.f, 0.f, 0.f);
            if (m < M) av = load4(A + (size_t)m * K + k0 + c4);
            As[c4 + 0][r] = av.x; As[c4 + 1][r] = av.y; As[c4 + 2][r] = av.z; As[c4 + 3][r] = av.w;
            int n = n0 + r;  // N is always a multiple of 128 here
            float4 bv = load4(W + (size_t)n * K + k0 + c4);
            Bs[c4 + 0][r] = bv.x; Bs[c4 + 1][r] = bv.y; Bs[c4 + 2][r] = bv.z; Bs[c4 + 3][r] = bv.w;
        }
        __syncthreads();
#pragma unroll
        for (int k = 0; k < 16; k++) {
            float a[8], b[8];
            *(float4*)&a[0] = *(const float4*)&As[k][ty * 8];
            *(float4*)&a[4] = *(const float4*)&As[k][ty * 8 + 4];
            *(float4*)&b[0] = *(const float4*)&Bs[k][tx * 8];
            *(float4*)&b[4] = *(const float4*)&Bs[k][tx * 8 + 4];
#pragma unroll
            for (int i = 0; i < 8; i++) {
#pragma unroll
                for (int j = 0; j < 8; j++) acc[i][j] += a[i] * b[j];
            }
        }
        __syncthreads();
    }
#pragma unroll
    for (int i = 0; i < 8; i++) {
        int m = m0 + ty * 8 + i;
        if (m < M) {
            float mrow[8];
            if constexpr (LORA) {
                float4 u = *(const float4*)&mid[(size_t)m * 8];
                float4 v = *(const float4*)&mid[(size_t)m * 8 + 4];
                mrow[0] = u.x; mrow[1] = u.y; mrow[2] = u.z; mrow[3] = u.w;
                mrow[4] = v.x; mrow[5] = v.y; mrow[6] = v.z; mrow[7] = v.w;
            }
#pragma unroll
            for (int j = 0; j < 8; j++) {
                int n = n0 + tx * 8 + j;
                float v = acc[i][j] + bias[n];
                if constexpr (LORA) {
                    const float4 l0 = *reinterpret_cast<const float4*>(lb + (size_t)n * 8);
                    const float4 l1 = *reinterpret_cast<const float4*>(lb + (size_t)n * 8 + 4);
                    v += mrow[0] * l0.x + mrow[1] * l0.y + mrow[2] * l0.z + mrow[3] * l0.w
                       + mrow[4] * l1.x + mrow[5] * l1.y + mrow[6] * l1.z + mrow[7] * l1.w;
                }
                storeC(C + (size_t)m * N + n, v);
            }
        }
    }
}

// ---------------- Fused per-frame attention: one block per (bb, h) ----------------
__global__ __launch_bounds__(256) void attn_kernel(const bf16* __restrict__ qkv,
        bf16* __restrict__ ao) {
    __shared__ bf16 Ks[TP * 66];   // padded stride 66 -> conflict-free paired reads
    __shared__ bf16 Vs[TP * 64];
    __shared__ float qs[4][64];
    __shared__ float sc[4][256];
    const int bb = blockIdx.x / NH;
    const int h = blockIdx.x % NH;
    const bf16* base = qkv + (size_t)bb * TP * N3;
    const int tid = threadIdx.x;
    for (int idx = tid; idx < TP * 32; idx += 256) {
        int kk = idx >> 5, d2 = (idx & 31) * 2;
        *(ushort2*)&Ks[kk * 66 + d2] =
            *(const ushort2*)(base + (size_t)kk * N3 + 768 + h * 64 + d2);
    }
    for (int idx = tid; idx < TP * 16; idx += 256) {
        int kk = idx >> 4, d4 = (idx & 15) * 4;
        *(ushort4*)&Vs[kk * 64 + d4] =
            *(const ushort4*)(base + (size_t)kk * N3 + 1536 + h * 64 + d4);
    }
    __syncthreads();
    const int w = tid >> 6, lane = tid & 63;
    for (int i = 0; i < 50; i++) {
        int p = i * 4 + w;
        if (p < TP) qs[w][lane] = b2f(base[(size_t)p * N3 + h * 64 + lane]);
        __syncthreads();
        float inv = 0.f;
        if (p < TP) {
            float sv[4];
            float mx = -1e30f;
#pragma unroll
            for (int j = 0; j < 4; j++) {
                int kk = j * 64 + lane;
                float s = -1e30f;
                if (kk < TP) {
                    const bf16* kr = Ks + kk * 66;
                    float a0 = 0.f;
#pragma unroll
                    for (int d2 = 0; d2 < 32; d2++) {
                        unsigned int u = *reinterpret_cast<const unsigned int*>(kr + 2 * d2);
                        a0 += qs[w][2 * d2] * __uint_as_float(u << 16);
                        a0 += qs[w][2 * d2 + 1] * __uint_as_float(u & 0xffff0000u);
                    }
                    s = a0 * SCALE;
                }
                sv[j] = s;
                mx = fmaxf(mx, s);
            }
#pragma unroll
            for (int off = 32; off >= 1; off >>= 1) mx = fmaxf(mx, __shfl_xor(mx, off, 64));
            float l = 0.f;
#pragma unroll
            for (int j = 0; j < 4; j++) {
                int kk = j * 64 + lane;
                if (kk < TP) {
                    float e = __expf(sv[j] - mx);
                    sc[w][kk] = e;
                    l += e;
                }
            }
#pragma unroll
            for (int off = 32; off >= 1; off >>= 1) l += __shfl_xor(l, off, 64);
            inv = 1.f / l;
        }
        __syncthreads();
        if (p < TP) {
            float o = 0.f;
            const int d = lane;
#pragma unroll 4
            for (int kk = 0; kk < TP; kk++)
                o += sc[w][kk] * b2f(Vs[kk * 64 + d]);
            ao[((size_t)bb * TP + p) * EDIM + h * 64 + d] = __float2bfloat16(o * inv);
        }
    }
}

// ---------------- Fused cross-frame CLS attention (flash-style online softmax) ----------
__global__ __launch_bounds__(256) void xattn_kernel(const bf16* __restrict__ qkv,
        float* __restrict__ x1p) {
    __shared__ float q1[NF][64];
    __shared__ bf16 Ks[128][64];
    __shared__ bf16 Vs[128][64];
    __shared__ float sc[NF][128];
    __shared__ float Oacc[NF][64];
    __shared__ float mrow[NF], lrow[NF], arow[NF];
    const int b = blockIdx.x / NH, h = blockIdx.x % NH;
    const int tid = threadIdx.x;
    for (int idx = tid; idx < NF * 64; idx += 256) {
        int f = idx >> 6, d = idx & 63;
        q1[f][d] = b2f(qkv[(size_t)((b * NF + f) * TP) * N3 + h * 64 + d]);
        Oacc[f][d] = 0.f;
    }
    if (tid < NF) { mrow[tid] = -1e30f; lrow[tid] = 0.f; }
    __syncthreads();
    const int w = tid >> 6, lane = tid & 63;
    for (int kk0 = 0; kk0 < KALL; kk0 += 128) {
        for (int idx = tid; idx < 128 * 16; idx += 256) {
            int r = idx >> 4, d4 = (idx & 15) * 4;
            int kk = kk0 + r;
            if (kk < KALL) {
                int f = kk / TP, pp = kk - f * TP;
                const bf16* src = qkv + (size_t)((b * NF + f) * TP + pp) * N3 + h * 64 + d4;
                *(ushort4*)&Ks[r][d4] = *(const ushort4*)(src + 768);
                *(ushort4*)&Vs[r][d4] = *(const ushort4*)(src + 1536);
            } else {
                ushort4 z; z.x = z.y = z.z = z.w = 0;
                *(ushort4*)&Ks[r][d4] = z;
                *(ushort4*)&Vs[r][d4] = z;
            }
        }
        __syncthreads();
        for (int idx = tid; idx < NF * 128; idx += 256) {
            int f = idx >> 7, r = idx & 127;
            float s = -1e30f;
            if (kk0 + r < KALL) {
                const bf16* kr = &Ks[r][0];
                float a = 0.f;
#pragma unroll
                for (int d2 = 0; d2 < 32; d2++) {
                    unsigned int u = *reinterpret_cast<const unsigned int*>(kr + 2 * d2);
                    a += q1[f][2 * d2] * __uint_as_float(u << 16);
                    a += q1[f][2 * d2 + 1] * __uint_as_float(u & 0xffff0000u);
                }
                s = a * SCALE;
            }
            sc[f][r] = s;
        }
        __syncthreads();
        for (int qi = 0; qi < 3; qi++) {
            int f = qi * 4 + w;
            float s0 = sc[f][lane], s1v = sc[f][lane + 64];
            float mx = fmaxf(s0, s1v);
#pragma unroll
            for (int off = 32; off >= 1; off >>= 1) mx = fmaxf(mx, __shfl_xor(mx, off, 64));
            float mold = mrow[f];
            float mnew = fmaxf(mold, mx);
            float e0 = __expf(s0 - mnew), e1 = __expf(s1v - mnew);
            float ls = e0 + e1;
#pragma unroll
            for (int off = 32; off >= 1; off >>= 1) ls += __shfl_xor(ls, off, 64);
            sc[f][lane] = e0; sc[f][lane + 64] = e1;
            if (lane == 0) {
                float alpha = __expf(mold - mnew);
                arow[f] = alpha;
                lrow[f] = lrow[f] * alpha + ls;
                mrow[f] = mnew;
            }
        }
        __syncthreads();
        for (int idx = tid; idx < NF * 64; idx += 256) {
            int f = idx >> 6, d = idx & 63;
            float o = Oacc[f][d] * arow[f];
#pragma unroll 4
            for (int r = 0; r < 128; r++)
                o += sc[f][r] * b2f(Vs[r][d]);
            Oacc[f][d] = o;
        }
        __syncthreads();
    }
    for (int idx = tid; idx < NF * 64; idx += 256) {
        int f = idx >> 6, d = idx & 63;
        x1p[(size_t)(b * NF + f) * EDIM + h * 64 + d] = Oacc[f][d] / lrow[f];
    }
}

// ---------------- CLS fixup: out[:,:,0,:] = MLP(out[:,:,0,:]) + x1p @ Wout^T + ob --------
__global__ __launch_bounds__(256) void cls_kernel(float* __restrict__ out,
        const float* __restrict__ x1p, const float* __restrict__ Wout, const float* __restrict__ ob,
        const float* __restrict__ dw, const float* __restrict__ db,
        const float* __restrict__ uw, const float* __restrict__ ub) {
    __shared__ float x0s[EDIM], x1s[EDIM], gs[8];
    const int bfi = blockIdx.x;
    float* row = out + (size_t)bfi * TP * EDIM;  // p = 0 row
    const int tid = threadIdx.x;
    for (int i = tid; i < EDIM; i += 256) {
        x0s[i] = row[i];
        x1s[i] = x1p[(size_t)bfi * EDIM + i];
    }
    __syncthreads();
    {
        int r = tid >> 5, sl = tid & 31;
        float pr = 0.f;
        for (int e = sl; e < EDIM; e += 32) pr += x0s[e] * dw[r * EDIM + e];
#pragma unroll
        for (int off = 16; off >= 1; off >>= 1) pr += __shfl_xor(pr, off, 64);
        if (sl == 0) gs[r] = pr + db[r];
    }
    __syncthreads();
    float act[8];
#pragma unroll
    for (int r = 0; r < 8; r++) { float g = gs[r]; act[r] = g / (1.f + __expf(-1.702f * g)); }
    for (int j = tid; j < EDIM; j += 256) {
        float y = ub[j] + ob[j];
        const float4 u0 = *reinterpret_cast<const float4*>(uw + (size_t)j * 8);
        const float4 u1 = *reinterpret_cast<const float4*>(uw + (size_t)j * 8 + 4);
        y += act[0] * u0.x + act[1] * u0.y + act[2] * u0.z + act[3] * u0.w
           + act[4] * u1.x + act[5] * u1.y + act[6] * u1.z + act[7] * u1.w;
        const float* wr = Wout + (size_t)j * EDIM;
        float s = 0.f;
        for (int e = 0; e < EDIM; e += 4) {
            float4 wv = *reinterpret_cast<const float4*>(wr + e);
            s += x1s[e] * wv.x + x1s[e + 1] * wv.y + x1s[e + 2] * wv.z + x1s[e + 3] * wv.w;
        }
        y += s;
        row[j] = y;
    }
}

extern "C" void kernel_launch(void* const* d_in, const int* in_sizes, int n_in,
                              void* d_out, int out_size, void* d_ws, size_t ws_size,
                              hipStream_t stream) {
    (void)in_sizes; (void)n_in; (void)out_size; (void)ws_size;
    const float* x   = (const float*)d_in[0];
    const float* ipw = (const float*)d_in[1];
    const float* ipb = (const float*)d_in[2];
    const float* opw = (const float*)d_in[3];
    const float* opb = (const float*)d_in[4];
    const float* la  = (const float*)d_in[5];
    const float* lb  = (const float*)d_in[6];
    const float* dw  = (const float*)d_in[7];
    const float* db  = (const float*)d_in[8];
    const float* uw  = (const float*)d_in[9];
    const float* ub  = (const float*)d_in[10];
    float* out = (float*)d_out;   // fp32 output per reference dtype

    // workspace: qkv bf16 174.3MB + ao bf16 58.1MB + mid fp32 1.2MB + x1p 0.6MB = 234.2MB
    char* wsb = (char*)d_ws;
    bf16* qkv = (bf16*)wsb;                       wsb += (size_t)NT * N3 * sizeof(bf16);
    bf16* ao  = (bf16*)wsb;                       wsb += (size_t)NT * EDIM * sizeof(bf16);
    float* mid = (float*)wsb;                     wsb += (size_t)NT * 8 * sizeof(float);
    float* x1p = (float*)wsb;                     wsb += (size_t)NB * NF * EDIM * sizeof(float);

    lora_mid_kernel<<<NT / 4, 256, 0, stream>>>(x, la, mid);
    gemm_kernel<float, bf16, true><<<dim3(N3 / 128, (NT + 127) / 128), 256, 0, stream>>>(
        x, ipw, ipb, mid, lb, qkv, NT, N3, EDIM);
    attn_kernel<<<192 * NH, 256, 0, stream>>>(qkv, ao);
    xattn_kernel<<<NB * NH, 256, 0, stream>>>(qkv, x1p);
    gemm_kernel<bf16, float, false><<<dim3(EDIM / 128, (NT + 127) / 128), 256, 0, stream>>>(
        ao, opw, opb, nullptr, nullptr, out, NT, EDIM, EDIM);
    cls_kernel<<<NB * NF, 256, 0, stream>>>(out, x1p, opw, opb, dw, db, uw, ub);
}